// Round 13
// baseline (1762.474 us; speedup 1.0000x reference)
//
#include <hip/hip_runtime.h>
#include <hip/hip_bf16.h>

// GCN over Block-CSR adjacency. ALL I/O BUFFERS ARE FLOAT32 (reference dtypes).
// Compute: bf16 MFMA, fp32 accumulate; intermediates stored bf16.
//
// Round 19: mega-kernel, gemm WITHOUT aw double-buffer (fits the 64-VGPR alloc).
// R17/R18 evidence: allocator pins the whole kernel at VGPR=64 no matter what
// (launch_bounds(256,4) and waves_per_eu(4,4) both ignored for budget); the
// gemm body's aw[2][8] dbuf = 64 VGPR alone -> guaranteed spills -> 4x latency
// from in-loop scratch reloads (FETCH +130MB, WRITE +81MB of scratch I/O).
// Fix at source: single aw[KS] buffer per iteration (~58 regs total) -> fits 64
// with ZERO spills; the lost ILP is covered by TLP (16 waves/CU in mega config).
// Arithmetic unchanged -> absmax must stay EXACTLY 0.005859375.
// Spill-free signals: FETCH ~0.91GB, WRITE ~310MB. Predicted dur 410-460us.
// Falsifier (pre-committed): FETCH ~1.0GB or dur>=500 -> revert R13, declare.
//
// ws (128 MiB): zbt0@[64,128) -> h0@[0,64) -> zbt1@[64,128) -> h1@[0,64) ->
// zbt2@[64,80). d_out written only in S6 (+ 64B barrier tail, memset + S6).

typedef __bf16 bf16;
typedef bf16 bf16x8 __attribute__((ext_vector_type(8)));
typedef bf16 bf16x4 __attribute__((ext_vector_type(4)));
typedef float f32x4 __attribute__((ext_vector_type(4)));

#define N_NODES 131072
#define BRQ 8192      // block rows (= N/16)
#define KNZ 8         // nonzero blocks per block row
#define IN_F 128
#define HID 256
#define NCLS 64
#define NWG 1024      // grid size = 256 CU x 4 WG/CU, all co-resident

static __device__ __forceinline__ f32x4 mfma16(bf16x8 a, bf16x8 b, f32x4 c) {
  return __builtin_amdgcn_mfma_f32_16x16x32_bf16(a, b, c, 0, 0, 0);
}

static __device__ __forceinline__ bf16x8 load8(const bf16* p) {
  return *(const bf16x8*)p;
}
static __device__ __forceinline__ bf16x8 cvt8(f32x4 a0, f32x4 a1) {
  bf16x8 r;
  r[0] = (bf16)a0[0]; r[1] = (bf16)a0[1]; r[2] = (bf16)a0[2]; r[3] = (bf16)a0[3];
  r[4] = (bf16)a1[0]; r[5] = (bf16)a1[1]; r[6] = (bf16)a1[2]; r[7] = (bf16)a1[3];
  return r;
}
static __device__ __forceinline__ bf16x8 load8(const float* p) {
  f32x4 a0 = *(const f32x4*)p;
  f32x4 a1 = *(const f32x4*)(p + 4);
  return cvt8(a0, a1);
}

// ---------------- generation-based grid barrier (R17-proven, verbatim) -----------
static __device__ __forceinline__ void grid_bar(unsigned* cnt, unsigned* gen) {
  __syncthreads();                       // whole WG arrived
  if (threadIdx.x == 0) {
    __threadfence();                     // release this WG's prior writes (L2 wb)
    unsigned g = __hip_atomic_load(gen, __ATOMIC_RELAXED, __HIP_MEMORY_SCOPE_AGENT);
    unsigned arrived =
        __hip_atomic_fetch_add(cnt, 1u, __ATOMIC_ACQ_REL, __HIP_MEMORY_SCOPE_AGENT);
    if (arrived == NWG - 1) {
      __hip_atomic_store(cnt, 0u, __ATOMIC_RELAXED, __HIP_MEMORY_SCOPE_AGENT);
      __hip_atomic_fetch_add(gen, 1u, __ATOMIC_RELEASE, __HIP_MEMORY_SCOPE_AGENT);
    } else {
      while (__hip_atomic_load(gen, __ATOMIC_ACQUIRE, __HIP_MEMORY_SCOPE_AGENT) == g)
        __builtin_amdgcn_s_sleep(8);
    }
    __threadfence();                     // acquire other WGs' writes (L2 inv)
  }
  __syncthreads();
}

// ---------------- dense GEMM stage body: single-buffer aw (fits 64 VGPR) ---------
template<typename TA, int KIN, int FOUT, int GRID>
static __device__ __forceinline__ void gemm_body(int wgid, int tid,
                                                 const TA* __restrict__ X,
                                                 const float* __restrict__ W,
                                                 bf16* __restrict__ Zbt,
                                                 bf16* WL) {
  constexpr int CG  = FOUT / 64;
  constexpr int KS  = KIN / 32;
  constexpr int WGR = GRID / CG;
  constexpr int RTS = WGR * 4;
  constexpr int NT  = BRQ / RTS;
  constexpr int LDW = KIN + 8;

  const int wave = tid >> 6;
  const int lane = tid & 63;
  const int l15  = lane & 15;
  const int quad = lane >> 4;
  const int cg   = wgid % CG;
  const int rg   = wgid / CG;
  const int rt0  = rg * 4 + wave;

  for (int e = tid; e < 64 * KIN; e += 256) {
    int c = e & 63, k = e >> 6;
    WL[c * LDW + k] = (bf16)W[(long)k * FOUT + cg * 64 + c];
  }

  const TA* __restrict__ xbase = X + (long)l15 * KIN + quad * 8;

  __syncthreads();   // WL staged

#pragma unroll
  for (int it = 0; it < NT; ++it) {
    const int rt = rt0 + it * RTS;
    // single-buffer A-row loads (same data, same order as dbuf version:
    // arithmetic bit-identical; ILP traded for TLP at 16 waves/CU)
    bf16x8 aw[KS];
#pragma unroll
    for (int k = 0; k < KS; ++k)
      aw[k] = load8(xbase + (long)rt * (16 * KIN) + k * 32);

    f32x4 acc[4] = {};
    unsigned lo = 0;
#pragma unroll
    for (int k = 0; k < KS; ++k) {
      asm volatile("" : "+v"(lo));   // block LICM re-hoist of W frags (R13-proven)
#pragma unroll
      for (int t = 0; t < 4; ++t) {
        bf16x8 wf = *(const bf16x8*)(WL + lo + (t * 16 + l15) * LDW + k * 32 + quad * 8);
        acc[t] = mfma16(aw[k], wf, acc[t]);
      }
    }
#pragma unroll
    for (int t = 0; t < 4; ++t) {
      int col = cg * 64 + t * 16 + l15;
      bf16x4 v;
#pragma unroll
      for (int i = 0; i < 4; ++i) v[i] = (bf16)acc[t][i];
      *(bf16x4*)(Zbt + ((long)rt * FOUT + col) * 16 + quad * 4) = v;
    }
  }
  __syncthreads();   // WL safe to reuse after return
}

// ---------------- SpMM + bias + ReLU + LayerNorm stage body (champion, verbatim) -
static __device__ __forceinline__ void spmm_ln_body(int wgid, int tid,
    const float* __restrict__ Abv, const int* __restrict__ Abc,
    const bf16* __restrict__ Zbt, const float* __restrict__ bias,
    const float* __restrict__ gamma, const float* __restrict__ beta,
    bf16* __restrict__ H, float* S, float* SS) {     // S,SS: [4][16] in LDS
  const int wave = tid >> 6;
  const int lane = tid & 63;
  const int l15  = lane & 15;
  const int quad = lane >> 4;
  const int b    = wgid * 2 + (wave >> 1);
  const int ch   = wave & 1;

  const int*   bc    = Abc + b * KNZ;
  const int    cst   = (quad & 1) * 8;
  const int    half  = quad >> 1;
  const float* abase = Abv + (long)b * (KNZ * 256) + l15 * 16 + cst;

  bf16x8 afr[4];
  long   zb[4];
#pragma unroll
  for (int kp = 0; kp < 4; ++kp) {
    int blk = 2 * kp + half;
    afr[kp] = load8(abase + blk * 256);
    zb[kp]  = (long)bc[blk] * (HID * 16) + cst;
  }
  bf16x8 bfr[4][8];
#pragma unroll
  for (int kp = 0; kp < 4; ++kp)
#pragma unroll
    for (int t = 0; t < 8; ++t) {
      int f = ch * 128 + t * 16 + l15;
      bfr[kp][t] = *(const bf16x8*)(Zbt + zb[kp] + f * 16);
    }

  f32x4 acc[8] = {};
#pragma unroll
  for (int kp = 0; kp < 4; ++kp)
#pragma unroll
    for (int t = 0; t < 8; ++t)
      acc[t] = mfma16(afr[kp], bfr[kp][t], acc[t]);

  float gv[8], bv[8];
#pragma unroll
  for (int t = 0; t < 8; ++t) {
    int f = ch * 128 + t * 16 + l15;
    gv[t] = gamma[f];
    bv[t] = beta[f];
  }
  float ps[4] = {0.f, 0.f, 0.f, 0.f}, pss[4] = {0.f, 0.f, 0.f, 0.f};
#pragma unroll
  for (int t = 0; t < 8; ++t) {
    float bi = bias[ch * 128 + t * 16 + l15];
#pragma unroll
    for (int i = 0; i < 4; ++i) {
      float v = acc[t][i] + bi;
      v = v > 0.f ? v : 0.f;
      acc[t][i] = v;
      ps[i] += v;
      pss[i] += v * v;
    }
  }
#pragma unroll
  for (int m = 1; m < 16; m <<= 1) {
#pragma unroll
    for (int i = 0; i < 4; ++i) {
      ps[i]  += __shfl_xor(ps[i], m, 64);
      pss[i] += __shfl_xor(pss[i], m, 64);
    }
  }
  if (l15 == 0) {
#pragma unroll
    for (int i = 0; i < 4; ++i) {
      S[wave * 16 + quad * 4 + i]  = ps[i];
      SS[wave * 16 + quad * 4 + i] = pss[i];
    }
  }
  __syncthreads();
#pragma unroll
  for (int i = 0; i < 4; ++i) {
    int r = quad * 4 + i;
    float s    = S[wave * 16 + r] + S[(wave ^ 1) * 16 + r];
    float ss   = SS[wave * 16 + r] + SS[(wave ^ 1) * 16 + r];
    float mu   = s * (1.f / 256.f);
    float var  = ss * (1.f / 256.f) - mu * mu;
    float rstd = rsqrtf(var + 1e-5f);
    bf16* hrow = H + (long)(b * 16 + r) * HID;
#pragma unroll
    for (int t = 0; t < 8; ++t) {
      int f = ch * 128 + t * 16 + l15;
      float y = (acc[t][i] - mu) * rstd * gv[t] + bv[t];
      hrow[f] = (bf16)y;
    }
  }
  __syncthreads();   // protect S/SS reuse by the next grid-stride iteration
}

// ---------------- final SpMM + bias stage body (champion, verbatim) --------------
static __device__ __forceinline__ void spmm_out_body(int wgid, int tid,
    const float* __restrict__ Abv, const int* __restrict__ Abc,
    const bf16* __restrict__ Zbt, const float* __restrict__ bias,
    float* __restrict__ out) {
  const int wave = tid >> 6;
  const int b    = wgid * 4 + wave;
  const int lane = tid & 63;
  const int l15  = lane & 15;
  const int quad = lane >> 4;

  const int*   bc    = Abc + b * KNZ;
  const int    cst   = (quad & 1) * 8;
  const int    half  = quad >> 1;
  const float* abase = Abv + (long)b * (KNZ * 256) + l15 * 16 + cst;

  bf16x8 afr[4];
  long   zb[4];
#pragma unroll
  for (int kp = 0; kp < 4; ++kp) {
    int blk = 2 * kp + half;
    afr[kp] = load8(abase + blk * 256);
    zb[kp]  = (long)bc[blk] * (NCLS * 16) + cst;
  }
  bf16x8 bfr[4][4];
#pragma unroll
  for (int kp = 0; kp < 4; ++kp)
#pragma unroll
    for (int t = 0; t < 4; ++t) {
      int f = t * 16 + l15;
      bfr[kp][t] = *(const bf16x8*)(Zbt + zb[kp] + f * 16);
    }

  f32x4 acc[4] = {};
#pragma unroll
  for (int kp = 0; kp < 4; ++kp)
#pragma unroll
    for (int t = 0; t < 4; ++t)
      acc[t] = mfma16(afr[kp], bfr[kp][t], acc[t]);

#pragma unroll
  for (int t = 0; t < 4; ++t) {
    int f = t * 16 + l15;
    float bi = bias[f];
#pragma unroll
    for (int i = 0; i < 4; ++i) {
      out[(long)(b * 16 + quad * 4 + i) * NCLS + f] = acc[t][i] + bi;
    }
  }
}

// ---------------- the mega-kernel (regular launch) -------------------------------
__global__ __launch_bounds__(256, 4) void mega(
    const float* __restrict__ features, const float* __restrict__ bvals,
    const float* __restrict__ W0, const float* __restrict__ b0v,
    const float* __restrict__ W1, const float* __restrict__ b1v,
    const float* __restrict__ W2, const float* __restrict__ b2v,
    const float* __restrict__ g0, const float* __restrict__ beta0,
    const float* __restrict__ g1, const float* __restrict__ beta1,
    const int* __restrict__ bcols,
    bf16* zbt0, bf16* zbt1, bf16* zbt2, bf16* h0, bf16* h1,
    float* outp, unsigned* bar) {
  __shared__ __align__(16) char LB[33792];   // WL (max 64*264*2) ; spmm S/SS overlap
  bf16*  WL = (bf16*)LB;
  float* S  = (float*)LB;
  float* SS = (float*)(LB + 256);

  unsigned* cnt = bar;       // zeroed by stream-ordered memset in kernel_launch
  unsigned* gen = bar + 1;

  const int wg  = blockIdx.x;
  const int tid = threadIdx.x;

  // S1: zbt0 = features @ W0
  gemm_body<float, IN_F, HID, NWG>(wg, tid, features, W0, zbt0, WL);
  grid_bar(cnt, gen);
  // S2: h0 = LN(relu(A @ zbt0 + b0))
  for (int i = wg; i < BRQ / 2; i += NWG)
    spmm_ln_body(i, tid, bvals, bcols, zbt0, b0v, g0, beta0, h0, S, SS);
  grid_bar(cnt, gen);
  // S3: zbt1 = h0 @ W1
  gemm_body<bf16, HID, HID, NWG>(wg, tid, h0, W1, zbt1, WL);
  grid_bar(cnt, gen);
  // S4: h1 = LN(relu(A @ zbt1 + b1))
  for (int i = wg; i < BRQ / 2; i += NWG)
    spmm_ln_body(i, tid, bvals, bcols, zbt1, b1v, g1, beta1, h1, S, SS);
  grid_bar(cnt, gen);
  // S5: zbt2 = h1 @ W2  (CG=1: every WG stages W2, NT=2)
  gemm_body<bf16, HID, NCLS, NWG>(wg, tid, h1, W2, zbt2, WL);
  grid_bar(cnt, gen);
  // S6: out = A @ zbt2 + b2   (d_out writes only after the final barrier)
  for (int i = wg; i < BRQ / 4; i += NWG)
    spmm_out_body(i, tid, bvals, bcols, zbt2, b2v, outp);
}

extern "C" void kernel_launch(void* const* d_in, const int* in_sizes, int n_in,
                              void* d_out, int out_size, void* d_ws, size_t ws_size,
                              hipStream_t stream) {
  const float* features = (const float*)d_in[0];
  const float* bvals    = (const float*)d_in[1];
  const float* W0       = (const float*)d_in[2];
  const float* b0v      = (const float*)d_in[3];
  const float* W1       = (const float*)d_in[4];
  const float* b1v      = (const float*)d_in[5];
  const float* W2       = (const float*)d_in[6];
  const float* b2v      = (const float*)d_in[7];
  const float* g0       = (const float*)d_in[8];
  const float* beta0    = (const float*)d_in[9];
  const float* g1       = (const float*)d_in[10];
  const float* beta1    = (const float*)d_in[11];
  const int*   bcols    = (const int*)d_in[12];
  float* outp = (float*)d_out;

  // ws (128 MiB), disjoint lifetimes (identical to R13):
  char* ws = (char*)d_ws;
  bf16* zbt0 = (bf16*)(ws + (64L << 20));    // [64,128)  S1 -> S2
  bf16* h0   = (bf16*)ws;                    // [0,64)    S2 -> S3
  bf16* zbt1 = (bf16*)(ws + (64L << 20));    // [64,128)  S3 -> S4 (over dead zbt0)
  bf16* h1   = (bf16*)ws;                    // [0,64)    S4 -> S5 (over dead h0)
  bf16* zbt2 = (bf16*)(ws + (64L << 20));    // [64,80)   S5 -> S6 (over dead zbt1)

  // barrier state: last 64 B of d_out. Zeroed stream-ordered before the kernel;
  // only S6 (post-final-barrier) writes d_out, so barriers 1-5 are undisturbed.
  const size_t out_bytes = (size_t)N_NODES * NCLS * sizeof(float);
  unsigned* bar = (unsigned*)((char*)d_out + out_bytes - 64);
  hipMemsetAsync((void*)bar, 0, 64, stream);

  mega<<<dim3(NWG), dim3(256), 0, stream>>>(
      features, bvals, W0, b0v, W1, b1v, W2, b2v, g0, beta0, g1, beta1,
      bcols, zbt0, zbt1, zbt2, h0, h1, outp, bar);
}

// Round 14
// 446.114 us; speedup vs baseline: 3.9507x; 3.9507x over previous
//
#include <hip/hip_runtime.h>
#include <hip/hip_bf16.h>

// GCN over Block-CSR adjacency. ALL I/O BUFFERS ARE FLOAT32 (reference dtypes).
// Compute: bf16 MFMA, fp32 accumulate; intermediates stored bf16.
//
// Round 20: REVERT to R13 (best passing, 445.7us) per R19's pre-committed
// falsifier. Final evidence ledger:
//  - spmm_ln is pinned at the 3.9 TB/s mixed-gather pattern ceiling: 6 schedule
//    variants (reg-pipeline, LDS-DMA, gather-fused, row-local-fused, mega x3)
//    all <= champion; dur == (FETCH+WRITE)/3.9TB/s invariantly.
//  - byte cuts: bf16-A net-negative (prep cost > spmm win, R11/R12); h-in-LDS
//    fusion halves effective BW by serializing gather issue (R15); L0 reorder
//    net-negative (R11).
//  - dispatch cuts: software grid barrier costs ~220us/barrier (cross-XCD
//    same-line atomics + spin-acquire L2 thrash) vs ~10us/bubble saved (R17-19).
//  - the one win kept: gemm_lds (LDS-staged W, 16 waves/CU) = +17us vs champion.
// Pipeline: gemm0 -> spmm_ln -> gemm1 -> spmm_ln -> gemm2 -> spmm_out.
// Expected: dur ~445us, absmax exactly 0.005859375.
//
// ws (128 MiB): zbt0@[64,128) -> h0@[0,64) -> zbt1@[64,128) -> h1@[0,64) ->
// zbt2@[64,80). d_out written only by spmm_out.

typedef __bf16 bf16;
typedef bf16 bf16x8 __attribute__((ext_vector_type(8)));
typedef bf16 bf16x4 __attribute__((ext_vector_type(4)));
typedef float f32x4 __attribute__((ext_vector_type(4)));

#define N_NODES 131072
#define BRQ 8192      // block rows (= N/16)
#define KNZ 8         // nonzero blocks per block row
#define IN_F 128
#define HID 256
#define NCLS 64

static __device__ __forceinline__ f32x4 mfma16(bf16x8 a, bf16x8 b, f32x4 c) {
  return __builtin_amdgcn_mfma_f32_16x16x32_bf16(a, b, c, 0, 0, 0);
}

static __device__ __forceinline__ bf16x8 load8(const bf16* p) {
  return *(const bf16x8*)p;
}
static __device__ __forceinline__ bf16x8 cvt8(f32x4 a0, f32x4 a1) {
  bf16x8 r;
  r[0] = (bf16)a0[0]; r[1] = (bf16)a0[1]; r[2] = (bf16)a0[2]; r[3] = (bf16)a0[3];
  r[4] = (bf16)a1[0]; r[5] = (bf16)a1[1]; r[6] = (bf16)a1[2]; r[7] = (bf16)a1[3];
  return r;
}
static __device__ __forceinline__ bf16x8 load8(const float* p) {
  f32x4 a0 = *(const f32x4*)p;
  f32x4 a1 = *(const f32x4*)(p + 4);
  return cvt8(a0, a1);
}

// ---------------- dense GEMM: LDS-staged W (high occupancy) ----------------------
// Zbt[rt][col][r] = X[N,KIN] @ W[KIN,FOUT]; W read f32 directly, transposed into
// LDS as bf16 [64][KIN+8] per WG (one col-group per WG, shared by its 4 waves).
template<typename TA, int KIN, int FOUT, int GRID>
__global__ __launch_bounds__(256, 4) void gemm_lds(const TA* __restrict__ X,
                                                   const float* __restrict__ W,
                                                   bf16* __restrict__ Zbt) {
  constexpr int CG  = FOUT / 64;          // 64-col groups
  constexpr int KS  = KIN / 32;           // K steps
  constexpr int WGR = GRID / CG;          // WGs per col group
  constexpr int RTS = WGR * 4;            // row-tile stride
  constexpr int NT  = BRQ / RTS;          // row-tiles per wave
  constexpr int LDW = KIN + 8;            // LDS row stride (+16B pad: 2-way banks)

  const int tid  = threadIdx.x;
  const int wave = tid >> 6;
  const int lane = tid & 63;
  const int l15  = lane & 15;
  const int quad = lane >> 4;
  const int cg   = blockIdx.x % CG;       // consecutive wgids share X row-tiles
  const int rg   = blockIdx.x / CG;
  const int rt0  = rg * 4 + wave;

  __shared__ bf16 WL[64 * LDW];

  // stage W^T col-block: WL[c][k] = W[k][cg*64+c]  (coalesced f32 reads over c)
  for (int e = tid; e < 64 * KIN; e += 256) {
    int c = e & 63, k = e >> 6;
    WL[c * LDW + k] = (bf16)W[(long)k * FOUT + cg * 64 + c];
  }

  const TA* __restrict__ xbase = X + (long)l15 * KIN + quad * 8;

  bf16x8 aw[2][KS];
#pragma unroll
  for (int k = 0; k < KS; ++k)
    aw[0][k] = load8(xbase + (long)rt0 * (16 * KIN) + k * 32);

  __syncthreads();   // prologue only; in-loop LDS is read-only -> no barriers

#pragma unroll
  for (int it = 0; it < NT; ++it) {
    const int rt = rt0 + it * RTS;
    if (it + 1 < NT) {
      const long xoff = (long)(rt + RTS) * (16 * KIN);
#pragma unroll
      for (int k = 0; k < KS; ++k)
        aw[(it + 1) & 1][k] = load8(xbase + xoff + k * 32);
    }
    f32x4 acc[4] = {};
    unsigned lo = 0;
#pragma unroll
    for (int k = 0; k < KS; ++k) {
      asm volatile("" : "+v"(lo));   // opaque offset: blocks LICM re-hoist of W frags
#pragma unroll
      for (int t = 0; t < 4; ++t) {
        bf16x8 wf = *(const bf16x8*)(WL + lo + (t * 16 + l15) * LDW + k * 32 + quad * 8);
        acc[t] = mfma16(aw[it & 1][k], wf, acc[t]);
      }
    }
#pragma unroll
    for (int t = 0; t < 4; ++t) {
      int col = cg * 64 + t * 16 + l15;
      bf16x4 v;
#pragma unroll
      for (int i = 0; i < 4; ++i) v[i] = (bf16)acc[t][i];
      *(bf16x4*)(Zbt + ((long)rt * FOUT + col) * 16 + quad * 4) = v;
    }
  }
}

// ---------------- SpMM + bias + ReLU + LayerNorm (F = HID = 256) — CHAMPION ------
__global__ __launch_bounds__(256) void spmm_ln(const float* __restrict__ Abv,
                                               const int*   __restrict__ Abc,
                                               const bf16*  __restrict__ Zbt,
                                               const float* __restrict__ bias,
                                               const float* __restrict__ gamma,
                                               const float* __restrict__ beta,
                                               bf16* __restrict__ H) {
  const int wave = threadIdx.x >> 6;
  const int lane = threadIdx.x & 63;
  const int l15  = lane & 15;
  const int quad = lane >> 4;
  const int b    = blockIdx.x * 2 + (wave >> 1);
  const int ch   = wave & 1;               // column half

  const int*   bc    = Abc + b * KNZ;
  const int    cst   = (quad & 1) * 8;
  const int    half  = quad >> 1;
  const float* abase = Abv + (long)b * (KNZ * 256) + l15 * 16 + cst;

  bf16x8 afr[4];
  long   zb[4];
#pragma unroll
  for (int kp = 0; kp < 4; ++kp) {
    int blk = 2 * kp + half;
    afr[kp] = load8(abase + blk * 256);
    zb[kp]  = (long)bc[blk] * (HID * 16) + cst;
  }
  bf16x8 bfr[4][8];
#pragma unroll
  for (int kp = 0; kp < 4; ++kp)
#pragma unroll
    for (int t = 0; t < 8; ++t) {
      int f = ch * 128 + t * 16 + l15;
      bfr[kp][t] = *(const bf16x8*)(Zbt + zb[kp] + f * 16);
    }

  f32x4 acc[8] = {};
#pragma unroll
  for (int kp = 0; kp < 4; ++kp)
#pragma unroll
    for (int t = 0; t < 8; ++t)
      acc[t] = mfma16(afr[kp], bfr[kp][t], acc[t]);

  // bias + relu in-register, accumulate per-row partial sums
  float gv[8], bv[8];
#pragma unroll
  for (int t = 0; t < 8; ++t) {
    int f = ch * 128 + t * 16 + l15;
    gv[t] = gamma[f];
    bv[t] = beta[f];
  }
  float ps[4] = {0.f, 0.f, 0.f, 0.f}, pss[4] = {0.f, 0.f, 0.f, 0.f};
#pragma unroll
  for (int t = 0; t < 8; ++t) {
    float bi = bias[ch * 128 + t * 16 + l15];
#pragma unroll
    for (int i = 0; i < 4; ++i) {
      float v = acc[t][i] + bi;
      v = v > 0.f ? v : 0.f;
      acc[t][i] = v;
      ps[i] += v;
      pss[i] += v * v;
    }
  }
#pragma unroll
  for (int m = 1; m < 16; m <<= 1) {
#pragma unroll
    for (int i = 0; i < 4; ++i) {
      ps[i]  += __shfl_xor(ps[i], m, 64);
      pss[i] += __shfl_xor(pss[i], m, 64);
    }
  }
  __shared__ float S[4][16], SS[4][16];
  if (l15 == 0) {
#pragma unroll
    for (int i = 0; i < 4; ++i) {
      S[wave][quad * 4 + i]  = ps[i];
      SS[wave][quad * 4 + i] = pss[i];
    }
  }
  __syncthreads();
#pragma unroll
  for (int i = 0; i < 4; ++i) {
    int r = quad * 4 + i;
    float s    = S[wave][r] + S[wave ^ 1][r];
    float ss   = SS[wave][r] + SS[wave ^ 1][r];
    float mu   = s * (1.f / 256.f);
    float var  = ss * (1.f / 256.f) - mu * mu;
    float rstd = rsqrtf(var + 1e-5f);
    bf16* hrow = H + (long)(b * 16 + r) * HID;
#pragma unroll
    for (int t = 0; t < 8; ++t) {
      int f = ch * 128 + t * 16 + l15;
      float y = (acc[t][i] - mu) * rstd * gv[t] + bv[t];
      hrow[f] = (bf16)y;
    }
  }
}

// ---------------- final SpMM + bias (F = NCLS = 64), f32 out — CHAMPION ----------
__global__ __launch_bounds__(256) void spmm_out(const float* __restrict__ Abv,
                                                const int*   __restrict__ Abc,
                                                const bf16*  __restrict__ Zbt,  // [BRQ,64,16]
                                                const float* __restrict__ bias, // [64]
                                                float* __restrict__ out) {      // [N,64] f32
  const int wave = threadIdx.x >> 6;
  const int b    = blockIdx.x * 4 + wave;   // one block-row per wave
  const int lane = threadIdx.x & 63;
  const int l15  = lane & 15;
  const int quad = lane >> 4;

  const int*   bc    = Abc + b * KNZ;
  const int    cst   = (quad & 1) * 8;
  const int    half  = quad >> 1;
  const float* abase = Abv + (long)b * (KNZ * 256) + l15 * 16 + cst;

  bf16x8 afr[4];
  long   zb[4];
#pragma unroll
  for (int kp = 0; kp < 4; ++kp) {
    int blk = 2 * kp + half;
    afr[kp] = load8(abase + blk * 256);
    zb[kp]  = (long)bc[blk] * (NCLS * 16) + cst;
  }
  bf16x8 bfr[4][4];
#pragma unroll
  for (int kp = 0; kp < 4; ++kp)
#pragma unroll
    for (int t = 0; t < 4; ++t) {
      int f = t * 16 + l15;
      bfr[kp][t] = *(const bf16x8*)(Zbt + zb[kp] + f * 16);
    }

  f32x4 acc[4] = {};
#pragma unroll
  for (int kp = 0; kp < 4; ++kp)
#pragma unroll
    for (int t = 0; t < 4; ++t)
      acc[t] = mfma16(afr[kp], bfr[kp][t], acc[t]);

#pragma unroll
  for (int t = 0; t < 4; ++t) {
    int f = t * 16 + l15;
    float bi = bias[f];
#pragma unroll
    for (int i = 0; i < 4; ++i) {
      out[(long)(b * 16 + quad * 4 + i) * NCLS + f] = acc[t][i] + bi;
    }
  }
}

extern "C" void kernel_launch(void* const* d_in, const int* in_sizes, int n_in,
                              void* d_out, int out_size, void* d_ws, size_t ws_size,
                              hipStream_t stream) {
  const float* features = (const float*)d_in[0];
  const float* bvals    = (const float*)d_in[1];
  const float* W0       = (const float*)d_in[2];
  const float* b0v      = (const float*)d_in[3];
  const float* W1       = (const float*)d_in[4];
  const float* b1v      = (const float*)d_in[5];
  const float* W2       = (const float*)d_in[6];
  const float* b2v      = (const float*)d_in[7];
  const float* g0       = (const float*)d_in[8];
  const float* beta0    = (const float*)d_in[9];
  const float* g1       = (const float*)d_in[10];
  const float* beta1    = (const float*)d_in[11];
  const int*   bcols    = (const int*)d_in[12];
  float* outp = (float*)d_out;

  // ws (128 MiB), disjoint lifetimes:
  char* ws = (char*)d_ws;
  bf16* zbt0 = (bf16*)(ws + (64L << 20));    // [64,128)  gemm0    -> spmm_ln0
  bf16* h0   = (bf16*)ws;                    // [0,64)    spmm_ln0 -> gemm1
  bf16* zbt1 = (bf16*)(ws + (64L << 20));    // [64,128)  gemm1    -> spmm_ln1
  bf16* h1   = (bf16*)ws;                    // [0,64)    spmm_ln1 -> gemm2
  bf16* zbt2 = (bf16*)(ws + (64L << 20));    // [64,80)   gemm2    -> spmm_out

  // L0
  gemm_lds<float, IN_F, HID, 1024><<<dim3(1024), dim3(256), 0, stream>>>(features, W0, zbt0);
  spmm_ln<<<dim3(BRQ / 2), dim3(256), 0, stream>>>(bvals, bcols, zbt0, b0v, g0, beta0, h0);
  // L1
  gemm_lds<bf16, HID, HID, 1024><<<dim3(1024), dim3(256), 0, stream>>>(h0, W1, zbt1);
  spmm_ln<<<dim3(BRQ / 2), dim3(256), 0, stream>>>(bvals, bcols, zbt1, b1v, g1, beta1, h1);
  // OUT
  gemm_lds<bf16, HID, NCLS, 512><<<dim3(512), dim3(256), 0, stream>>>(h1, W2, zbt2);
  spmm_out<<<dim3(BRQ / 4), dim3(256), 0, stream>>>(bvals, bcols, zbt2, b2v, outp);
}